// Round 4
// baseline (477.449 us; speedup 1.0000x reference)
//
#include <hip/hip_runtime.h>

// DistMult edge score: out[e] = sum_d node_emb[src[e]][d] * rel_emb[e][d] * node_emb[dst[e]][d]
// N_NODES = 100000, N_EDGES = 600000, DIM = 128, all fp32, indices int32.
//
// R3: half-wave (32 lanes) per edge-group, but each group now processes 4
// edges, issuing all 12 global loads (3 per edge) before any reduction —
// 4x memory-level parallelism per wave to hide the ~200-cyc L2/L3 gather
// latency. rel_emb (307 MB zero-reuse stream) stays non-temporal so the
// 51 MB node_emb table stays cache-resident. Total traffic unchanged.
//
// Known fixed overhead: the timed region includes the harness's 1.2 GB
// d_ws poison (~188 us) + input restore (~116 us); kernel itself is the
// remainder (<187 us — never appears in rocprof top-5).

#define DIM 128
#define EDGES_PER_GROUP 4
#define GROUPS_PER_BLOCK 8   // 256 threads / 32 lanes

typedef float vfloat4 __attribute__((ext_vector_type(4)));

__global__ __launch_bounds__(256) void distmult_score_kernel(
    const float* __restrict__ node_emb,
    const float* __restrict__ rel_emb,
    const int*   __restrict__ src,
    const int*   __restrict__ dst,
    float*       __restrict__ out,
    int E)
{
    const int tid  = threadIdx.x;     // 0..255
    const int grp  = tid >> 5;        // 0..7
    const int lane = tid & 31;        // 0..31 : float4 slot within a 128-dim row

    const int e0 = (blockIdx.x * GROUPS_PER_BLOCK + grp) * EDGES_PER_GROUP;

    vfloat4 h[EDGES_PER_GROUP], r[EDGES_PER_GROUP], t[EDGES_PER_GROUP];

    // Phase 1: issue ALL loads for the 4 edges (12 independent 16B loads/lane).
    #pragma unroll
    for (int i = 0; i < EDGES_PER_GROUP; ++i) {
        const int e = e0 + i;
        if (e < E) {
            const int s = src[e];
            const int d = dst[e];
            h[i] = ((const vfloat4*)(node_emb + (size_t)s * DIM))[lane];
            t[i] = ((const vfloat4*)(node_emb + (size_t)d * DIM))[lane];
            r[i] = __builtin_nontemporal_load(
                       (const vfloat4*)(rel_emb + (size_t)e * DIM) + lane);
        }
    }

    // Phase 2: reduce each edge; compiler waits on each edge's loads as needed.
    #pragma unroll
    for (int i = 0; i < EDGES_PER_GROUP; ++i) {
        const int e = e0 + i;
        if (e >= E) continue;
        float v = h[i].x * r[i].x * t[i].x
                + h[i].y * r[i].y * t[i].y
                + h[i].z * r[i].z * t[i].z
                + h[i].w * r[i].w * t[i].w;
        #pragma unroll
        for (int off = 16; off > 0; off >>= 1)
            v += __shfl_xor(v, off, 32);
        if (lane == 0) __builtin_nontemporal_store(v, out + e);
    }
}

extern "C" void kernel_launch(void* const* d_in, const int* in_sizes, int n_in,
                              void* d_out, int out_size, void* d_ws, size_t ws_size,
                              hipStream_t stream) {
    const float* node_emb = (const float*)d_in[0];
    const float* rel_emb  = (const float*)d_in[1];
    const int*   src      = (const int*)d_in[2];
    const int*   dst      = (const int*)d_in[3];
    float*       out      = (float*)d_out;

    const int E = in_sizes[2];  // 600000 edges

    const int edges_per_block = GROUPS_PER_BLOCK * EDGES_PER_GROUP;  // 32
    const int grid = (E + edges_per_block - 1) / edges_per_block;
    distmult_score_kernel<<<grid, 256, 0, stream>>>(node_emb, rel_emb, src, dst, out, E);
}

// Round 5
// 468.310 us; speedup vs baseline: 1.0195x; 1.0195x over previous
//
#include <hip/hip_runtime.h>

// DistMult edge score: out[e] = sum_d node_emb[src[e]][d] * rel_emb[e][d] * node_emb[dst[e]][d]
// N_NODES = 100000, N_EDGES = 600000, DIM = 128, all fp32, indices int32.
//
// Final form (R4): half-wave (32 lanes) per edge; each lane loads one float4
// from head/rel/tail (16 B/lane, fully coalesced — one 512 B row per group);
// 5-step shuffle reduce; lane 0 stores the score.
//
// rel_emb (307 MB, zero reuse) is loaded non-temporally so the 51 MB node_emb
// gather working set stays L2/L3-resident.
//
// Measured context: timed region includes ~300+ us of fixed harness restore/
// poison traffic (1.23 GB fills at ~6.6 TB/s dominate rocprof top-5); kernel
// contribution is < 183 us vs a ~58 us compulsory-traffic floor. R0-R3 all
// landed in the 459-477 us noise band regardless of kernel-side changes.

#define DIM 128
#define EDGES_PER_BLOCK 8

typedef float vfloat4 __attribute__((ext_vector_type(4)));

__global__ __launch_bounds__(256) void distmult_score_kernel(
    const float* __restrict__ node_emb,
    const float* __restrict__ rel_emb,
    const int*   __restrict__ src,
    const int*   __restrict__ dst,
    float*       __restrict__ out,
    int E)
{
    const int tid  = threadIdx.x;     // 0..255
    const int grp  = tid >> 5;        // 0..7 : edge within block
    const int lane = tid & 31;        // 0..31 : float4 slot within row

    const int e = blockIdx.x * EDGES_PER_BLOCK + grp;
    if (e >= E) return;               // uniform within each 32-lane group

    const int s = src[e];
    const int d = dst[e];

    // Streaming operand: non-temporal (don't evict the node table).
    const vfloat4 r = __builtin_nontemporal_load(
        (const vfloat4*)(rel_emb + (size_t)e * DIM) + lane);
    // Reused operands: normal cached loads.
    const vfloat4 h = ((const vfloat4*)(node_emb + (size_t)s * DIM))[lane];
    const vfloat4 t = ((const vfloat4*)(node_emb + (size_t)d * DIM))[lane];

    float v = h.x * r.x * t.x
            + h.y * r.y * t.y
            + h.z * r.z * t.z
            + h.w * r.w * t.w;

    #pragma unroll
    for (int off = 16; off > 0; off >>= 1)
        v += __shfl_xor(v, off, 32);

    if (lane == 0) out[e] = v;
}

extern "C" void kernel_launch(void* const* d_in, const int* in_sizes, int n_in,
                              void* d_out, int out_size, void* d_ws, size_t ws_size,
                              hipStream_t stream) {
    const float* node_emb = (const float*)d_in[0];
    const float* rel_emb  = (const float*)d_in[1];
    const int*   src      = (const int*)d_in[2];
    const int*   dst      = (const int*)d_in[3];
    float*       out      = (float*)d_out;

    const int E = in_sizes[2];  // 600000 edges

    const int grid = (E + EDGES_PER_BLOCK - 1) / EDGES_PER_BLOCK;
    distmult_score_kernel<<<grid, 256, 0, stream>>>(node_emb, rel_emb, src, dst, out, E);
}